// Round 1
// baseline (53911.401 us; speedup 1.0000x reference)
//
#include <hip/hip_runtime.h>

#define GRAV 9.80665f

__device__ __forceinline__ float sel3(int r, float a0, float a1, float a2){
  float x = (r==1)? a1 : a0;
  return (r>=2)? a2 : x;
}

__device__ __forceinline__ void mm33(float* __restrict__ O, const float* A, const float* B){
#pragma unroll
  for(int r=0;r<3;++r){
#pragma unroll
    for(int c=0;c<3;++c){
      O[r*3+c] = A[r*3+0]*B[0*3+c] + A[r*3+1]*B[1*3+c] + A[r*3+2]*B[2*3+c];
    }
  }
}

// R = c*I + k1*phi phi^T + k2*skew(phi); Taylor for small t=|phi|^2, exact otherwise.
__device__ __forceinline__ void rot_from_t2(float t_, float p0, float p1, float p2, float* R){
  float c_, k1_, k2_;
  if (t_ < 1e-4f){
    c_  = 1.f - t_*(0.5f - t_*((1.f/24.f) - t_*(1.f/720.f)));
    k2_ = 1.f - t_*((1.f/6.f) - t_*((1.f/120.f) - t_*(1.f/5040.f)));
    k1_ = 0.5f - t_*((1.f/24.f) - t_*(1.f/720.f));
  } else {
    float a = sqrtf(t_);
    c_ = __cosf(a);
    float s = __sinf(a);
    k2_ = s/a;
    k1_ = (1.f - c_)/t_;
  }
  R[0]=c_+k1_*p0*p0;      R[1]=k1_*p0*p1-k2_*p2;  R[2]=k1_*p0*p2+k2_*p1;
  R[3]=k1_*p0*p1+k2_*p2;  R[4]=c_+k1_*p1*p1;      R[5]=k1_*p1*p2-k2_*p0;
  R[6]=k1_*p0*p2-k2_*p1;  R[7]=k1_*p1*p2+k2_*p0;  R[8]=c_+k1_*p2*p2;
}

__device__ __forceinline__ void normalize_rot9(float* X){
#pragma unroll 1
  for(int it=0; it<8; ++it){
    float Y[9], Z[9];
#pragma unroll
    for(int r=0;r<3;++r)
#pragma unroll
      for(int c=0;c<3;++c)
        Y[r*3+c] = X[r*3+0]*X[c*3+0] + X[r*3+1]*X[c*3+1] + X[r*3+2]*X[c*3+2];
#pragma unroll
    for(int r=0;r<3;++r)
#pragma unroll
      for(int c=0;c<3;++c)
        Z[r*3+c] = Y[r*3+0]*X[0*3+c] + Y[r*3+1]*X[1*3+c] + Y[r*3+2]*X[2*3+c];
#pragma unroll
    for(int e=0;e<9;++e) X[e] = 1.5f*X[e] - 0.5f*Z[e];
  }
}

__device__ __forceinline__ float pick_state(int l,
    const float* Rt, const float* vv, const float* pp,
    const float* bw, const float* ba, const float* Rc, const float* tc){
  float s = Rt[0];
  s=(l==1)?Rt[1]:s;  s=(l==2)?Rt[2]:s;  s=(l==3)?Rt[3]:s;  s=(l==4)?Rt[4]:s;
  s=(l==5)?Rt[5]:s;  s=(l==6)?Rt[6]:s;  s=(l==7)?Rt[7]:s;  s=(l==8)?Rt[8]:s;
  s=(l==9)?vv[0]:s;  s=(l==10)?vv[1]:s; s=(l==11)?vv[2]:s;
  s=(l==12)?pp[0]:s; s=(l==13)?pp[1]:s; s=(l==14)?pp[2]:s;
  s=(l==15)?bw[0]:s; s=(l==16)?bw[1]:s; s=(l==17)?bw[2]:s;
  s=(l==18)?ba[0]:s; s=(l==19)?ba[1]:s; s=(l==20)?ba[2]:s;
  s=(l==21)?Rc[0]:s; s=(l==22)?Rc[1]:s; s=(l==23)?Rc[2]:s;
  s=(l==24)?Rc[3]:s; s=(l==25)?Rc[4]:s; s=(l==26)?Rc[5]:s;
  s=(l==27)?Rc[6]:s; s=(l==28)?Rc[7]:s; s=(l==29)?Rc[8]:s;
  s=(l==30)?tc[0]:s; s=(l==31)?tc[1]:s; s=(l==32)?tc[2]:s;
  return s;
}

__global__ __launch_bounds__(64,1)
void iekf_scan_kernel(const float* __restrict__ t,
                      const float* __restrict__ u,
                      const float* __restrict__ mcov,
                      const float* __restrict__ v_mes,
                      const float* __restrict__ ang0,
                      float* __restrict__ out, int N)
{
  const int l = threadIdx.x;
  __shared__ float Pm[441];   // canonical P (becomes M=P+GQG^T in place)
  __shared__ float Eb[441];   // E = Phi @ M
  __shared__ float PnS[441];  // P_n, then T1=(I-KH)P_n in place
  __shared__ float PuS[441];  // P_u before symmetrization
  __shared__ float HPs[42];   // H @ P_n   [r*21+c]
  __shared__ float Ks[42];    // K         [i*2+a]
  __shared__ float Ws[42];    // T1 @ H^T  [i*2+r]
  __shared__ float dxs[21];

  // ---- initial state (uniform across lanes) ----
  float Rt[9], vv[3], pp[3], bw[3], ba[3], Rc[9], tc[3];
  {
    float rl = ang0[0], pt = ang0[1], yw = ang0[2];
    float cr=cosf(rl), sr=sinf(rl), cp=cosf(pt), sp=sinf(pt), cy=cosf(yw), sy=sinf(yw);
    Rt[0]=cy*cp; Rt[1]=cy*sp*sr - sy*cr; Rt[2]=cy*sp*cr + sy*sr;
    Rt[3]=sy*cp; Rt[4]=sy*sp*sr + cy*cr; Rt[5]=sy*sp*cr - cy*sr;
    Rt[6]=-sp;   Rt[7]=cp*sr;            Rt[8]=cp*cr;
  }
  vv[0]=v_mes[0]; vv[1]=v_mes[1]; vv[2]=v_mes[2];
#pragma unroll
  for(int k=0;k<3;++k){ pp[k]=0.f; bw[k]=0.f; ba[k]=0.f; tc[k]=0.f; }
  Rc[0]=1.f;Rc[1]=0.f;Rc[2]=0.f;Rc[3]=0.f;Rc[4]=1.f;Rc[5]=0.f;Rc[6]=0.f;Rc[7]=0.f;Rc[8]=1.f;

  // ---- init covariance ----
  for (int e=l; e<441; e+=64){
    int r=e/21, c=e-(e/21)*21;
    float vI=0.f;
    if (r==c){
      if (r<2) vI=0.001f;
      else if (r==3||r==4) vI=0.1f;
      else if (r>=9&&r<12) vI=0.006f;
      else if (r>=12&&r<15) vI=0.004f;
      else if (r>=15&&r<18) vI=1e-6f;
      else if (r>=18) vI=0.005f;
    }
    Pm[e]=vI;
  }

  // ---- per-lane output mapping ----
  int ostr=0; float* op = out;
  {
    int obase=0, ooff=0;
    if (l<9)       {obase=0;    ostr=9; ooff=l;}
    else if (l<12) {obase=9*N;  ostr=3; ooff=l-9;}
    else if (l<15) {obase=12*N; ostr=3; ooff=l-12;}
    else if (l<18) {obase=15*N; ostr=3; ooff=l-15;}
    else if (l<21) {obase=18*N; ostr=3; ooff=l-18;}
    else if (l<30) {obase=21*N; ostr=9; ooff=l-21;}
    else           {obase=30*N; ostr=3; ooff=l-30;}
    op = out + obase + ooff;
  }

  // ---- stage-A (GQG^T) per-lane constants ----
  int idxA=0, rrA=0, ccA=0; float qvA=0.f; bool rrtA=false;
  if (l<9)      { rrA=l/3; ccA=l-rrA*3; idxA=rrA*21+ccA; qvA=0.001f; rrtA=true; }
  else if (l<18){ int m=l-9; rrA=m/3; ccA=m-rrA*3; idxA=(3+rrA)*21+(3+ccA); qvA=0.01f; rrtA=true; }
  else if (l<30){ int j=l-18; int b=j/3, d=j-b*3; int row=9+b*3+d; idxA=row*21+row;
                  qvA = (b==0)?6e-9f : (b==1)?2e-4f : 1e-9f; }

  const int g21 = l/21;        // lane group 0..3 (3 only for lane 63)
  const int c21 = l - g21*21;  // 0..20

  static const int cols[12] = {3,4,5, 9,10,11, 15,16,17, 18,19,20};

  // ---- row 0 outputs ----
  {
    float sv = pick_state(l, Rt, vv, pp, bw, ba, Rc, tc);
    if (l<33) op[0] = sv;
  }
  __syncthreads();

  // ---- prefetch for i=1 ----
  float tA = t[0], tB = t[1];
  float cu[6];
#pragma unroll
  for(int k=0;k<6;++k) cu[k]=u[6+k];
  float cm0=mcov[2], cm1=mcov[3];

  int nx100=100, nx1000=1000;

#pragma unroll 1
  for (int i=1; i<N; ++i){
    float dt = tB - tA;
    float u0=cu[0], u1=cu[1], u2=cu[2], u3=cu[3], u4=cu[4], u5=cu[5];
    float crm0=cm0, crm1=cm1;
    if (i+1 < N){
      tA = tB; tB = t[i+1];
#pragma unroll
      for(int k=0;k<6;++k) cu[k]=u[(i+1)*6+k];
      cm0 = mcov[(i+1)*2]; cm1 = mcov[(i+1)*2+1];
    }
    float dt2=dt*dt, gdt=GRAV*dt, hdt=0.5f*dt, g6=gdt*dt*(1.0f/6.0f), hdt2=0.5f*dt*dt;

    // ===== uniform small math (all lanes redundant) =====
    float w0=u0-bw[0], w1=u1-bw[1], w2=u2-bw[2];
    float aa0=u3-ba[0], aa1=u4-ba[1], aa2=u5-ba[2];
    float acc0 = Rt[0]*aa0+Rt[1]*aa1+Rt[2]*aa2;
    float acc1 = Rt[3]*aa0+Rt[4]*aa1+Rt[5]*aa2;
    float acc2 = Rt[6]*aa0+Rt[7]*aa1+Rt[8]*aa2 - GRAV;
    float vn0=vv[0]+acc0*dt, vn1=vv[1]+acc1*dt, vn2=vv[2]+acc2*dt;
    float pn0=pp[0]+vv[0]*dt+acc0*hdt2;
    float pn1=pp[1]+vv[1]*dt+acc1*hdt2;
    float pn2=pp[2]+vv[2]*dt+acc2*hdt2;
    float ph0=w0*dt, ph1=w1*dt, ph2=w2*dt;
    float dRs[9]; rot_from_t2(ph0*ph0+ph1*ph1+ph2*ph2, ph0,ph1,ph2, dRs);
    float Rn[9]; mm33(Rn, Rt, dRs);          // Rot_n
    float Rb[9]; mm33(Rb, Rn, Rc);           // Rot_body
    float vi0 = Rn[0]*vn0+Rn[3]*vn1+Rn[6]*vn2;  // v_imu = Rot_n^T v_n
    float vi1 = Rn[1]*vn0+Rn[4]*vn1+Rn[7]*vn2;
    float vi2 = Rn[2]*vn0+Rn[5]*vn1+Rn[8]*vn2;
    float vb1 = Rc[1]*vi0+Rc[4]*vi1+Rc[7]*vi2 + (tc[2]*w0 - tc[0]*w2);
    float vb2 = Rc[2]*vi0+Rc[5]*vi1+Rc[8]*vi2 + (tc[0]*w1 - tc[1]*w0);
    float rr0 = -vb1, rr1 = -vb2;

    float H0[12], H1[12];
    H0[0]=Rb[1]; H0[1]=Rb[4]; H0[2]=Rb[7];
    H1[0]=Rb[2]; H1[1]=Rb[5]; H1[2]=Rb[8];
    H0[3]=tc[2];  H0[4]=0.f;   H0[5]=-tc[0];
    H1[3]=-tc[1]; H1[4]=tc[0]; H1[5]=0.f;
    H0[6]=Rc[4]*vi2 - Rc[7]*vi1;  H0[7]=Rc[7]*vi0 - Rc[1]*vi2;  H0[8]=Rc[1]*vi1 - Rc[4]*vi0;
    H1[6]=Rc[5]*vi2 - Rc[8]*vi1;  H1[7]=Rc[8]*vi0 - Rc[2]*vi2;  H1[8]=Rc[2]*vi1 - Rc[5]*vi0;
    H0[9]=-w2; H0[10]=0.f; H0[11]=w0;
    H1[9]=w1;  H1[10]=-w0; H1[11]=0.f;

    // Phi off-diag blocks (uniform): B=-Rot*dt, Cab=C+AB/2, D2=D+dtC/2+dtAB/6
    float Bm[9], Cab[9], D2a[9];
#pragma unroll
    for(int k=0;k<3;++k){
      float b0=-dt*Rt[k], b1=-dt*Rt[3+k], b2=-dt*Rt[6+k];
      float c0=dt*(vv[2]*Rt[3+k]-vv[1]*Rt[6+k]);
      float c1=dt*(vv[0]*Rt[6+k]-vv[2]*Rt[k]);
      float c2=dt*(vv[1]*Rt[k]-vv[0]*Rt[3+k]);
      float d0=dt*(pp[2]*Rt[3+k]-pp[1]*Rt[6+k]);
      float d1=dt*(pp[0]*Rt[6+k]-pp[2]*Rt[k]);
      float d2=dt*(pp[1]*Rt[k]-pp[0]*Rt[3+k]);
      Bm[k]=b0; Bm[3+k]=b1; Bm[6+k]=b2;
      Cab[k]=c0+0.5f*gdt*b1; Cab[3+k]=c1-0.5f*gdt*b0; Cab[6+k]=c2;
      D2a[k]=d0+hdt*c0+g6*b1; D2a[3+k]=d1+hdt*c1-g6*b0; D2a[6+k]=d2+hdt*c2;
    }
    float Bs0=sel3(g21,Bm[0],Bm[3],Bm[6]),  Bs1=sel3(g21,Bm[1],Bm[4],Bm[7]),  Bs2=sel3(g21,Bm[2],Bm[5],Bm[8]);
    float Cs0=sel3(g21,Cab[0],Cab[3],Cab[6]),Cs1=sel3(g21,Cab[1],Cab[4],Cab[7]),Cs2=sel3(g21,Cab[2],Cab[5],Cab[8]);
    float Ds0=sel3(g21,D2a[0],D2a[3],D2a[6]),Ds1=sel3(g21,D2a[1],D2a[4],D2a[7]),Ds2=sel3(g21,D2a[2],D2a[5],D2a[8]);

    // ===== stage A: M = P + GQG^T (in place, 30 lanes) =====
    if (l<30){
      float addv;
      if (rrtA){
        float ra0=sel3(rrA,Rt[0],Rt[3],Rt[6]), ra1=sel3(rrA,Rt[1],Rt[4],Rt[7]), ra2=sel3(rrA,Rt[2],Rt[5],Rt[8]);
        float rb0=sel3(ccA,Rt[0],Rt[3],Rt[6]), rb1=sel3(ccA,Rt[1],Rt[4],Rt[7]), rb2=sel3(ccA,Rt[2],Rt[5],Rt[8]);
        addv = qvA*dt2*(ra0*rb0+ra1*rb1+ra2*rb2);
      } else addv = qvA*dt2;
      Pm[idxA] += addv;
    }
    __syncthreads();

    // ===== stage E: E = Phi @ M (rows 0..8 computed; rows 9..20 copied) =====
    if (l<63){
      int c = c21;
      float m0 = Pm[c], m1 = Pm[21+c];
      float mr = Pm[g21*21+c], m3r = Pm[(3+g21)*21+c], m6r = Pm[(6+g21)*21+c];
      float m9 =Pm[9*21+c],  m10=Pm[10*21+c], m11=Pm[11*21+c];
      float m12=Pm[12*21+c], m13=Pm[13*21+c], m14=Pm[14*21+c];
      float Ar = (g21==0)? gdt*m1 : (g21==1)? -gdt*m0 : 0.f;
      float bterm = Bs0*m12+Bs1*m13+Bs2*m14;
      float e0 = mr + Bs0*m9+Bs1*m10+Bs2*m11;
      float e1 = m3r + Ar + Cs0*m9+Cs1*m10+Cs2*m11 + bterm;
      float e2 = m6r + hdt*Ar + dt*m3r + Ds0*m9+Ds1*m10+Ds2*m11 + hdt*bterm;
      Eb[g21*21+c]=e0; Eb[(3+g21)*21+c]=e1; Eb[(6+g21)*21+c]=e2;
      int rw = 9+4*g21;
      Eb[rw*21+c]     = Pm[rw*21+c];
      Eb[(rw+1)*21+c] = Pm[(rw+1)*21+c];
      Eb[(rw+2)*21+c] = Pm[(rw+2)*21+c];
      Eb[(rw+3)*21+c] = Pm[(rw+3)*21+c];
    }
    __syncthreads();

    // ===== stage Pn: P_n = E @ Phi^T (cols 0..8 computed; 9..20 copied) =====
    if (l<63){
      int r = c21;
      const float* Er = Eb + r*21;
      float e0a=Er[0], e1a=Er[1];
      float eg=Er[g21], e3g=Er[3+g21], e6g=Er[6+g21];
      float e9=Er[9],e10=Er[10],e11=Er[11],e12=Er[12],e13=Er[13],e14=Er[14];
      float Ag = (g21==0)? gdt*e1a : (g21==1)? -gdt*e0a : 0.f;
      float bterm = Bs0*e12+Bs1*e13+Bs2*e14;
      float q0 = eg + Bs0*e9+Bs1*e10+Bs2*e11;
      float q1 = e3g + Ag + Cs0*e9+Cs1*e10+Cs2*e11 + bterm;
      float q2 = e6g + hdt*Ag + dt*e3g + Ds0*e9+Ds1*e10+Ds2*e11 + hdt*bterm;
      PnS[r*21+g21]=q0; PnS[r*21+3+g21]=q1; PnS[r*21+6+g21]=q2;
      int cw = 9+4*g21;
      PnS[r*21+cw]=Er[cw]; PnS[r*21+cw+1]=Er[cw+1]; PnS[r*21+cw+2]=Er[cw+2]; PnS[r*21+cw+3]=Er[cw+3];
    }
    __syncthreads();

    // ===== stage HP: HP = H @ P_n (12 nonzero H cols) =====
    if (l<42){
      int rH = l/21, c = l-(l/21)*21;
      float acc = 0.f;
#pragma unroll
      for(int k=0;k<12;++k){
        float h = (rH==0)? H0[k] : H1[k];
        acc += h * PnS[cols[k]*21 + c];
      }
      HPs[rH*21+c] = acc;
    }
    __syncthreads();

    // ===== stage S/K/dx =====
    float s00=crm0, s11=crm1, s01=0.f, s10=0.f;
#pragma unroll
    for(int k=0;k<12;++k){
      float hp0 = HPs[cols[k]];
      float hp1 = HPs[21+cols[k]];
      s00 += hp0*H0[k]; s01 += hp0*H1[k];
      s10 += hp1*H0[k]; s11 += hp1*H1[k];
    }
    float idet = 1.0f/(s00*s11 - s01*s10);
    float i00 =  s11*idet, i01 = -s01*idet, i10 = -s10*idet, i11 = s00*idet;
    if (l<21){
      float hp0=HPs[l], hp1=HPs[21+l];
      float K0 = i00*hp0 + i01*hp1;
      float K1 = i10*hp0 + i11*hp1;
      Ks[l*2]=K0; Ks[l*2+1]=K1;
      dxs[l] = K0*rr0 + K1*rr1;
    }
    __syncthreads();

    // read dx (uniform broadcast)
    float dxr[21];
#pragma unroll
    for(int k=0;k<21;++k) dxr[k]=dxs[k];

    // ===== stage T1: P_n -= K @ HP (in place) =====
    if (l<63){
      int c = c21;
      float hp0 = HPs[c], hp1 = HPs[21+c];
#pragma unroll
      for (int rrow=0; rrow<7; ++rrow){
        int r = g21*7+rrow;
        float k0=Ks[r*2], k1=Ks[r*2+1];
        PnS[r*21+c] -= k0*hp0 + k1*hp1;
      }
    }
    __syncthreads();

    // ===== stage W: W = T1 @ H^T =====
    if (l<42){
      int rW = l/21, ii = l-(l/21)*21;
      float acc=0.f;
#pragma unroll
      for(int k=0;k<12;++k){
        float h = (rW==0)? H0[k] : H1[k];
        acc += PnS[ii*21+cols[k]] * h;
      }
      Ws[ii*2+rW]=acc;
    }
    __syncthreads();

    // ===== stage Pu: P_u = T1 - W K^T + K Rm K^T =====
    if (l<63){
      int c = c21;
      float kc0=Ks[c*2], kc1=Ks[c*2+1];
#pragma unroll
      for(int rrow=0;rrow<7;++rrow){
        int r = g21*7+rrow;
        float w0_=Ws[r*2], w1_=Ws[r*2+1];
        float kr0=Ks[r*2], kr1=Ks[r*2+1];
        float tv=PnS[r*21+c];
        PuS[r*21+c] = tv - (w0_*kc0+w1_*kc1) + crm0*kr0*kc0 + crm1*kr1*kc1;
      }
    }
    __syncthreads();

    // ===== stage Sym: P = 0.5 (P_u + P_u^T) =====
    if (l<63){
      int c = c21;
#pragma unroll
      for(int rrow=0;rrow<7;++rrow){
        int r = g21*7+rrow;
        Pm[r*21+c] = 0.5f*(PuS[r*21+c] + PuS[c*21+r]);
      }
    }
    __syncthreads();

    // ===== state update (uniform) =====
    float t2x = dxr[0]*dxr[0]+dxr[1]*dxr[1]+dxr[2]*dxr[2];
    float cX,k1X,k2X,j1X;
    if (t2x < 1e-4f){
      cX  = 1.f - t2x*(0.5f - t2x*((1.f/24.f) - t2x*(1.f/720.f)));
      k2X = 1.f - t2x*((1.f/6.f) - t2x*((1.f/120.f) - t2x*(1.f/5040.f)));
      k1X = 0.5f - t2x*((1.f/24.f) - t2x*(1.f/720.f));
      j1X = (1.f/6.f) - t2x*((1.f/120.f) - t2x*(1.f/5040.f));
    } else {
      float a = sqrtf(t2x);
      cX = __cosf(a);
      float s = __sinf(a);
      k2X = s/a; k1X = (1.f-cX)/t2x; j1X = (1.f-k2X)/t2x;
    }
    float dR[9];
    dR[0]=cX+k1X*dxr[0]*dxr[0];      dR[1]=k1X*dxr[0]*dxr[1]-k2X*dxr[2]; dR[2]=k1X*dxr[0]*dxr[2]+k2X*dxr[1];
    dR[3]=k1X*dxr[0]*dxr[1]+k2X*dxr[2]; dR[4]=cX+k1X*dxr[1]*dxr[1];      dR[5]=k1X*dxr[1]*dxr[2]-k2X*dxr[0];
    dR[6]=k1X*dxr[0]*dxr[2]-k2X*dxr[1]; dR[7]=k1X*dxr[1]*dxr[2]+k2X*dxr[0]; dR[8]=cX+k1X*dxr[2]*dxr[2];
    float Jm[9];
    Jm[0]=k2X+j1X*dxr[0]*dxr[0];      Jm[1]=j1X*dxr[0]*dxr[1]-k1X*dxr[2]; Jm[2]=j1X*dxr[0]*dxr[2]+k1X*dxr[1];
    Jm[3]=j1X*dxr[0]*dxr[1]+k1X*dxr[2]; Jm[4]=k2X+j1X*dxr[1]*dxr[1];      Jm[5]=j1X*dxr[1]*dxr[2]-k1X*dxr[0];
    Jm[6]=j1X*dxr[0]*dxr[2]-k1X*dxr[1]; Jm[7]=j1X*dxr[1]*dxr[2]+k1X*dxr[0]; Jm[8]=k2X+j1X*dxr[2]*dxr[2];

    float Ru[9]; mm33(Ru, dR, Rn);
    float vu0 = dR[0]*vn0+dR[1]*vn1+dR[2]*vn2 + Jm[0]*dxr[3]+Jm[1]*dxr[4]+Jm[2]*dxr[5];
    float vu1 = dR[3]*vn0+dR[4]*vn1+dR[5]*vn2 + Jm[3]*dxr[3]+Jm[4]*dxr[4]+Jm[5]*dxr[5];
    float vu2 = dR[6]*vn0+dR[7]*vn1+dR[8]*vn2 + Jm[6]*dxr[3]+Jm[7]*dxr[4]+Jm[8]*dxr[5];
    float pu0 = dR[0]*pn0+dR[1]*pn1+dR[2]*pn2 + Jm[0]*dxr[6]+Jm[1]*dxr[7]+Jm[2]*dxr[8];
    float pu1 = dR[3]*pn0+dR[4]*pn1+dR[5]*pn2 + Jm[3]*dxr[6]+Jm[4]*dxr[7]+Jm[5]*dxr[8];
    float pu2 = dR[6]*pn0+dR[7]*pn1+dR[8]*pn2 + Jm[6]*dxr[6]+Jm[7]*dxr[7]+Jm[8]*dxr[8];
    bw[0]+=dxr[9];  bw[1]+=dxr[10]; bw[2]+=dxr[11];
    ba[0]+=dxr[12]; ba[1]+=dxr[13]; ba[2]+=dxr[14];
    float Ec[9]; rot_from_t2(dxr[15]*dxr[15]+dxr[16]*dxr[16]+dxr[17]*dxr[17], dxr[15],dxr[16],dxr[17], Ec);
    float Rcu[9]; mm33(Rcu, Ec, Rc);
    tc[0]+=dxr[18]; tc[1]+=dxr[19]; tc[2]+=dxr[20];

    if (i==nx100){ normalize_rot9(Ru); nx100+=100; }
    if (i==nx1000){ normalize_rot9(Rcu); nx1000+=1000; }

#pragma unroll
    for(int k=0;k<9;++k){ Rt[k]=Ru[k]; Rc[k]=Rcu[k]; }
    vv[0]=vu0; vv[1]=vu1; vv[2]=vu2;
    pp[0]=pu0; pp[1]=pu1; pp[2]=pu2;

    // ===== outputs =====
    float sv = pick_state(l, Rt, vv, pp, bw, ba, Rc, tc);
    if (l<33) op[i*ostr] = sv;
  }
}

extern "C" void kernel_launch(void* const* d_in, const int* in_sizes, int n_in,
                              void* d_out, int out_size, void* d_ws, size_t ws_size,
                              hipStream_t stream) {
  (void)n_in; (void)out_size; (void)d_ws; (void)ws_size;
  const float* t     = (const float*)d_in[0];
  const float* u     = (const float*)d_in[1];
  const float* mcov  = (const float*)d_in[2];
  const float* v_mes = (const float*)d_in[3];
  const float* ang0  = (const float*)d_in[5];
  int N = in_sizes[0];
  iekf_scan_kernel<<<dim3(1), dim3(64), 0, stream>>>(t, u, mcov, v_mes, ang0, (float*)d_out, N);
}

// Round 4
// 46050.031 us; speedup vs baseline: 1.1707x; 1.1707x over previous
//
#include <hip/hip_runtime.h>

#define GRAV 9.80665f

__device__ __forceinline__ float sel3(int r, float a0, float a1, float a2){
  float x = (r==1)? a1 : a0;
  return (r>=2)? a2 : x;
}

__device__ __forceinline__ void mm33(float* __restrict__ O, const float* A, const float* B){
#pragma unroll
  for(int r=0;r<3;++r){
#pragma unroll
    for(int c=0;c<3;++c){
      O[r*3+c] = A[r*3+0]*B[0*3+c] + A[r*3+1]*B[1*3+c] + A[r*3+2]*B[2*3+c];
    }
  }
}

// R = c*I + k1*phi phi^T + k2*skew(phi); Taylor for small t=|phi|^2, exact otherwise.
__device__ __forceinline__ void rot_from_t2(float t_, float p0, float p1, float p2, float* R){
  float c_, k1_, k2_;
  if (t_ < 1e-4f){
    c_  = 1.f - t_*(0.5f - t_*((1.f/24.f) - t_*(1.f/720.f)));
    k2_ = 1.f - t_*((1.f/6.f) - t_*((1.f/120.f) - t_*(1.f/5040.f)));
    k1_ = 0.5f - t_*((1.f/24.f) - t_*(1.f/720.f));
  } else {
    float a = sqrtf(t_);
    c_ = __cosf(a);
    float s = __sinf(a);
    k2_ = s/a;
    k1_ = (1.f - c_)/t_;
  }
  R[0]=c_+k1_*p0*p0;      R[1]=k1_*p0*p1-k2_*p2;  R[2]=k1_*p0*p2+k2_*p1;
  R[3]=k1_*p0*p1+k2_*p2;  R[4]=c_+k1_*p1*p1;      R[5]=k1_*p1*p2-k2_*p0;
  R[6]=k1_*p0*p2-k2_*p1;  R[7]=k1_*p1*p2+k2_*p0;  R[8]=c_+k1_*p2*p2;
}

__device__ __forceinline__ void normalize_rot9(float* X){
#pragma unroll 1
  for(int it=0; it<8; ++it){
    float Y[9], Z[9];
#pragma unroll
    for(int r=0;r<3;++r)
#pragma unroll
      for(int c=0;c<3;++c)
        Y[r*3+c] = X[r*3+0]*X[c*3+0] + X[r*3+1]*X[c*3+1] + X[r*3+2]*X[c*3+2];
#pragma unroll
    for(int r=0;r<3;++r)
#pragma unroll
      for(int c=0;c<3;++c)
        Z[r*3+c] = Y[r*3+0]*X[0*3+c] + Y[r*3+1]*X[1*3+c] + Y[r*3+2]*X[2*3+c];
#pragma unroll
    for(int e=0;e<9;++e) X[e] = 1.5f*X[e] - 0.5f*Z[e];
  }
}

__device__ __forceinline__ float pick_state(int l,
    const float* Rt, const float* vv, const float* pp,
    const float* bw, const float* ba, const float* Rc, const float* tc){
  float s = Rt[0];
  s=(l==1)?Rt[1]:s;  s=(l==2)?Rt[2]:s;  s=(l==3)?Rt[3]:s;  s=(l==4)?Rt[4]:s;
  s=(l==5)?Rt[5]:s;  s=(l==6)?Rt[6]:s;  s=(l==7)?Rt[7]:s;  s=(l==8)?Rt[8]:s;
  s=(l==9)?vv[0]:s;  s=(l==10)?vv[1]:s; s=(l==11)?vv[2]:s;
  s=(l==12)?pp[0]:s; s=(l==13)?pp[1]:s; s=(l==14)?pp[2]:s;
  s=(l==15)?bw[0]:s; s=(l==16)?bw[1]:s; s=(l==17)?bw[2]:s;
  s=(l==18)?ba[0]:s; s=(l==19)?ba[1]:s; s=(l==20)?ba[2]:s;
  s=(l==21)?Rc[0]:s; s=(l==22)?Rc[1]:s; s=(l==23)?Rc[2]:s;
  s=(l==24)?Rc[3]:s; s=(l==25)?Rc[4]:s; s=(l==26)?Rc[5]:s;
  s=(l==27)?Rc[6]:s; s=(l==28)?Rc[7]:s; s=(l==29)?Rc[8]:s;
  s=(l==30)?tc[0]:s; s=(l==31)?tc[1]:s; s=(l==32)?tc[2]:s;
  return s;
}

__global__ __launch_bounds__(64,1)
void iekf_scan_kernel(const float* __restrict__ t,
                      const float* __restrict__ u,
                      const float* __restrict__ mcov,
                      const float* __restrict__ v_mes,
                      const float* __restrict__ ang0,
                      float* __restrict__ out, int N)
{
  const int l = threadIdx.x;
  __shared__ float  Pm[441];    // canonical symmetric P
  __shared__ float  Eb[441];    // E = Phi @ M
  __shared__ float  PnS[441];   // P_n (raw, for transpose reads)
  __shared__ float2 HPs2[21];   // HP[:,c] pairs
  __shared__ float2 Ks2[21];    // K rows

  // ---- initial state (uniform across lanes) ----
  float Rt[9], vv[3], pp[3], bw[3], ba[3], Rc[9], tc[3];
  {
    float rl = ang0[0], pt = ang0[1], yw = ang0[2];
    float cr=cosf(rl), sr=sinf(rl), cp=cosf(pt), sp=sinf(pt), cy=cosf(yw), sy=sinf(yw);
    Rt[0]=cy*cp; Rt[1]=cy*sp*sr - sy*cr; Rt[2]=cy*sp*cr + sy*sr;
    Rt[3]=sy*cp; Rt[4]=sy*sp*sr + cy*cr; Rt[5]=sy*sp*cr - cy*sr;
    Rt[6]=-sp;   Rt[7]=cp*sr;            Rt[8]=cp*cr;
  }
  vv[0]=v_mes[0]; vv[1]=v_mes[1]; vv[2]=v_mes[2];
#pragma unroll
  for(int k=0;k<3;++k){ pp[k]=0.f; bw[k]=0.f; ba[k]=0.f; tc[k]=0.f; }
  Rc[0]=1.f;Rc[1]=0.f;Rc[2]=0.f;Rc[3]=0.f;Rc[4]=1.f;Rc[5]=0.f;Rc[6]=0.f;Rc[7]=0.f;Rc[8]=1.f;

  // ---- init covariance ----
  for (int e=l; e<441; e+=64){
    int r=e/21, c=e-(e/21)*21;
    float vI=0.f;
    if (r==c){
      if (r<2) vI=0.001f;
      else if (r==3||r==4) vI=0.1f;
      else if (r>=9&&r<12) vI=0.006f;
      else if (r>=12&&r<15) vI=0.004f;
      else if (r>=15&&r<18) vI=1e-6f;
      else if (r>=18) vI=0.005f;
    }
    Pm[e]=vI;
  }

  // ---- per-lane output mapping ----
  int ostr=0; float* op = out;
  {
    int obase=0, ooff=0;
    if (l<9)       {obase=0;    ostr=9; ooff=l;}
    else if (l<12) {obase=9*N;  ostr=3; ooff=l-9;}
    else if (l<15) {obase=12*N; ostr=3; ooff=l-12;}
    else if (l<18) {obase=15*N; ostr=3; ooff=l-15;}
    else if (l<21) {obase=18*N; ostr=3; ooff=l-18;}
    else if (l<30) {obase=21*N; ostr=9; ooff=l-21;}
    else           {obase=30*N; ostr=3; ooff=l-30;}
    op = out + obase + ooff;
  }

  const int g21 = l/21;        // group 0..2 (3 for lane 63, masked out)
  const int c21 = l - g21*21;  // 0..20 : column (stage E) / row (Pn,Pu)
  const int cw  = 9 + 4*g21;   // copy-block base row/col
  int l1 = l+21; if (l1>=63) l1-=63;
  int l2 = l+42; if (l2>=63) l2-=63;

  static const int cols[12] = {3,4,5, 9,10,11, 15,16,17, 18,19,20};

  // ---- row 0 outputs ----
  {
    float sv = pick_state(l, Rt, vv, pp, bw, ba, Rc, tc);
    if (l<33) op[0] = sv;
  }
  __syncthreads();

  // ---- prefetch for i=1 ----
  float tA = t[0], tB = t[1];
  float cu[6];
#pragma unroll
  for(int k=0;k<6;++k) cu[k]=u[6+k];
  float cm0=mcov[2], cm1=mcov[3];

  int nx100=100, nx1000=1000;

#pragma unroll 1
  for (int i=1; i<N; ++i){
    float dt = tB - tA;
    float u0=cu[0], u1=cu[1], u2=cu[2], u3=cu[3], u4=cu[4], u5=cu[5];
    float crm0=cm0, crm1=cm1;
    if (i+1 < N){
      tA = tB; tB = t[i+1];
#pragma unroll
      for(int k=0;k<6;++k) cu[k]=u[(i+1)*6+k];
      cm0 = mcov[(i+1)*2]; cm1 = mcov[(i+1)*2+1];
    }
    float dt2=dt*dt, gdt=GRAV*dt, hdt=0.5f*dt, g6=gdt*dt*(1.0f/6.0f), hdt2=0.5f*dt*dt;

    // ===== uniform small math (all lanes redundant) =====
    float w0=u0-bw[0], w1=u1-bw[1], w2=u2-bw[2];
    float aa0=u3-ba[0], aa1=u4-ba[1], aa2=u5-ba[2];
    float acc0 = Rt[0]*aa0+Rt[1]*aa1+Rt[2]*aa2;
    float acc1 = Rt[3]*aa0+Rt[4]*aa1+Rt[5]*aa2;
    float acc2 = Rt[6]*aa0+Rt[7]*aa1+Rt[8]*aa2 - GRAV;
    float vn0=vv[0]+acc0*dt, vn1=vv[1]+acc1*dt, vn2=vv[2]+acc2*dt;
    float pn0=pp[0]+vv[0]*dt+acc0*hdt2;
    float pn1=pp[1]+vv[1]*dt+acc1*hdt2;
    float pn2=pp[2]+vv[2]*dt+acc2*hdt2;
    float ph0=w0*dt, ph1=w1*dt, ph2=w2*dt;
    float dRs[9]; rot_from_t2(ph0*ph0+ph1*ph1+ph2*ph2, ph0,ph1,ph2, dRs);
    float Rn[9]; mm33(Rn, Rt, dRs);          // Rot_n
    float Rb[9]; mm33(Rb, Rn, Rc);           // Rot_body
    float vi0 = Rn[0]*vn0+Rn[3]*vn1+Rn[6]*vn2;  // v_imu = Rot_n^T v_n
    float vi1 = Rn[1]*vn0+Rn[4]*vn1+Rn[7]*vn2;
    float vi2 = Rn[2]*vn0+Rn[5]*vn1+Rn[8]*vn2;
    float vb1 = Rc[1]*vi0+Rc[4]*vi1+Rc[7]*vi2 + (tc[2]*w0 - tc[0]*w2);
    float vb2 = Rc[2]*vi0+Rc[5]*vi1+Rc[8]*vi2 + (tc[0]*w1 - tc[1]*w0);
    float rr0 = -vb1, rr1 = -vb2;

    float H0[12], H1[12];
    H0[0]=Rb[1]; H0[1]=Rb[4]; H0[2]=Rb[7];
    H1[0]=Rb[2]; H1[1]=Rb[5]; H1[2]=Rb[8];
    H0[3]=tc[2];  H0[4]=0.f;   H0[5]=-tc[0];
    H1[3]=-tc[1]; H1[4]=tc[0]; H1[5]=0.f;
    H0[6]=Rc[4]*vi2 - Rc[7]*vi1;  H0[7]=Rc[7]*vi0 - Rc[1]*vi2;  H0[8]=Rc[1]*vi1 - Rc[4]*vi0;
    H1[6]=Rc[5]*vi2 - Rc[8]*vi1;  H1[7]=Rc[8]*vi0 - Rc[2]*vi2;  H1[8]=Rc[2]*vi1 - Rc[5]*vi0;
    H0[9]=-w2; H0[10]=0.f; H0[11]=w0;
    H1[9]=w1;  H1[10]=-w0; H1[11]=0.f;

    // Phi off-diag blocks (uniform): B=-Rot*dt, Cab=C+AB/2, D2=D+dtC/2+dtAB/6
    float Bm[9], Cab[9], D2a[9];
#pragma unroll
    for(int k=0;k<3;++k){
      float b0=-dt*Rt[k], b1=-dt*Rt[3+k], b2=-dt*Rt[6+k];
      float c0=dt*(vv[2]*Rt[3+k]-vv[1]*Rt[6+k]);
      float c1=dt*(vv[0]*Rt[6+k]-vv[2]*Rt[k]);
      float c2=dt*(vv[1]*Rt[k]-vv[0]*Rt[3+k]);
      float d0=dt*(pp[2]*Rt[3+k]-pp[1]*Rt[6+k]);
      float d1=dt*(pp[0]*Rt[6+k]-pp[2]*Rt[k]);
      float d2=dt*(pp[1]*Rt[k]-pp[0]*Rt[3+k]);
      Bm[k]=b0; Bm[3+k]=b1; Bm[6+k]=b2;
      Cab[k]=c0+0.5f*gdt*b1; Cab[3+k]=c1-0.5f*gdt*b0; Cab[6+k]=c2;
      D2a[k]=d0+hdt*c0+g6*b1; D2a[3+k]=d1+hdt*c1-g6*b0; D2a[6+k]=d2+hdt*c2;
    }
    float Bs0=sel3(g21,Bm[0],Bm[3],Bm[6]),  Bs1=sel3(g21,Bm[1],Bm[4],Bm[7]),  Bs2=sel3(g21,Bm[2],Bm[5],Bm[8]);
    float Cs0=sel3(g21,Cab[0],Cab[3],Cab[6]),Cs1=sel3(g21,Cab[1],Cab[4],Cab[7]),Cs2=sel3(g21,Cab[2],Cab[5],Cab[8]);
    float Ds0=sel3(g21,D2a[0],D2a[3],D2a[6]),Ds1=sel3(g21,D2a[1],D2a[4],D2a[7]),Ds2=sel3(g21,D2a[2],D2a[5],D2a[8]);

    // GQG^T delta constants (uniform): RR^T and scaled q's
    float RRT00=Rt[0]*Rt[0]+Rt[1]*Rt[1]+Rt[2]*Rt[2];
    float RRT01=Rt[0]*Rt[3]+Rt[1]*Rt[4]+Rt[2]*Rt[5];
    float RRT02=Rt[0]*Rt[6]+Rt[1]*Rt[7]+Rt[2]*Rt[8];
    float RRT11=Rt[3]*Rt[3]+Rt[4]*Rt[4]+Rt[5]*Rt[5];
    float RRT12=Rt[3]*Rt[6]+Rt[4]*Rt[7]+Rt[5]*Rt[8];
    float RRT22=Rt[6]*Rt[6]+Rt[7]*Rt[7]+Rt[8]*Rt[8];
    float q0d=0.001f*dt2, q1d=0.01f*dt2;
    float q69=6e-9f*dt2, q24=2e-4f*dt2, q19=1e-9f*dt2;

    // ===== stage E: E = Phi @ (P + GQG^T), GQG^T folded into reads =====
    if (l<63){
      int c = c21;
      bool cl3 = (c<3);
      bool c36 = (c>=3 && c<6);
      float R0c  = sel3(c,   RRT00, RRT01, RRT02);
      float R1c  = sel3(c,   RRT01, RRT11, RRT12);
      float R2c  = sel3(c,   RRT02, RRT12, RRT22);
      float R0c3 = sel3(c-3, RRT00, RRT01, RRT02);
      float R1c3 = sel3(c-3, RRT01, RRT11, RRT12);
      float R2c3 = sel3(c-3, RRT02, RRT12, RRT22);
      float d0  = cl3 ? q0d*R0c : 0.f;
      float d1  = cl3 ? q0d*R1c : 0.f;
      float dg  = cl3 ? q0d*sel3(g21,R0c,R1c,R2c) : 0.f;
      float dg3 = c36 ? q1d*sel3(g21,R0c3,R1c3,R2c3) : 0.f;

      float m0  = Pm[c]            + d0;
      float m1  = Pm[21+c]         + d1;
      float mr  = Pm[g21*21+c]     + dg;
      float m3r = Pm[(3+g21)*21+c] + dg3;
      float m6r = Pm[(6+g21)*21+c];
      float m9  = Pm[9*21+c]  + ((c==9) ? q69 : 0.f);
      float m10 = Pm[10*21+c] + ((c==10)? q69 : 0.f);
      float m11 = Pm[11*21+c] + ((c==11)? q69 : 0.f);
      float m12 = Pm[12*21+c] + ((c==12)? q24 : 0.f);
      float m13 = Pm[13*21+c] + ((c==13)? q24 : 0.f);
      float m14 = Pm[14*21+c] + ((c==14)? q24 : 0.f);

      float Ar = (g21==0)? gdt*m1 : (g21==1)? -gdt*m0 : 0.f;
      float bterm = Bs0*m12+Bs1*m13+Bs2*m14;
      float e0 = mr + Bs0*m9+Bs1*m10+Bs2*m11;
      float e1 = m3r + Ar + Cs0*m9+Cs1*m10+Cs2*m11 + bterm;
      float e2 = m6r + hdt*Ar + dt*m3r + Ds0*m9+Ds1*m10+Ds2*m11 + hdt*bterm;
      Eb[g21*21+c]=e0; Eb[(3+g21)*21+c]=e1; Eb[(6+g21)*21+c]=e2;
#pragma unroll
      for (int jj=0;jj<4;++jj){
        int row = cw+jj;
        float qd = (row<12)? q69 : (row<15)? q24 : q19;
        Eb[row*21+c] = Pm[row*21+c] + ((row==c)? qd : 0.f);
      }
    }
    __syncthreads();  // W0

    // ===== stage Pn: row r of P_n in registers (+LDS for transpose) + HP partials =====
    float pnv[7];
#pragma unroll
    for(int k=0;k<7;++k) pnv[k]=0.f;
    float p0=0.f, p1=0.f;
    if (l<63){
      int r = c21;
      const float* Er = Eb + r*21;
      float e0a=Er[0], e1a=Er[1];
      float eg=Er[g21], e3g=Er[3+g21], e6g=Er[6+g21];
      float e9=Er[9],e10=Er[10],e11=Er[11],e12=Er[12],e13=Er[13],e14=Er[14];
      float Ag = (g21==0)? gdt*e1a : (g21==1)? -gdt*e0a : 0.f;
      float bterm = Bs0*e12+Bs1*e13+Bs2*e14;
      pnv[0] = eg + Bs0*e9+Bs1*e10+Bs2*e11;                             // col g
      pnv[1] = e3g + Ag + Cs0*e9+Cs1*e10+Cs2*e11 + bterm;               // col 3+g
      pnv[2] = e6g + hdt*Ag + dt*e3g + Ds0*e9+Ds1*e10+Ds2*e11 + hdt*bterm; // col 6+g
      pnv[3] = Er[cw]; pnv[4] = Er[cw+1]; pnv[5] = Er[cw+2]; pnv[6] = Er[cw+3];

      // store Pn row to LDS for bitwise-symmetric transpose reads in stage Pu
      PnS[r*21 + g21]     = pnv[0];
      PnS[r*21 + 3+g21]   = pnv[1];
      PnS[r*21 + 6+g21]   = pnv[2];
      PnS[r*21 + cw]      = pnv[3];
      PnS[r*21 + cw+1]    = pnv[4];
      PnS[r*21 + cw+2]    = pnv[5];
      PnS[r*21 + cw+3]    = pnv[6];

      // HP partial: this group's share of sum_k H[a,k]*Pn[r, cols[k]]
      float c1a = sel3(g21, H0[0], H0[1], H0[2]);
      float c3a = sel3(g21, H0[3], 0.f,   H0[8]);
      float c4a = sel3(g21, H0[4], 0.f,   H0[9]);
      float c5a = sel3(g21, H0[5], H0[6], H0[10]);
      float c6a = sel3(g21, 0.f,   H0[7], H0[11]);
      float c1b = sel3(g21, H1[0], H1[1], H1[2]);
      float c3b = sel3(g21, H1[3], 0.f,   H1[8]);
      float c4b = sel3(g21, H1[4], 0.f,   H1[9]);
      float c5b = sel3(g21, H1[5], H1[6], H1[10]);
      float c6b = sel3(g21, 0.f,   H1[7], H1[11]);
      p0 = c1a*pnv[1] + c3a*pnv[3] + c4a*pnv[4] + c5a*pnv[5] + c6a*pnv[6];
      p1 = c1b*pnv[1] + c3b*pnv[3] + c4b*pnv[4] + c5b*pnv[5] + c6b*pnv[6];
    }
    // combine partials across the 3 groups; every lane ends with HP[:,r], r=c21
    float hpr0 = p0 + __shfl(p0, l1) + __shfl(p0, l2);
    float hpr1 = p1 + __shfl(p1, l1) + __shfl(p1, l2);
    if (l<21) HPs2[c21] = make_float2(hpr0, hpr1);
    __syncthreads();  // W1

    // ===== stage S/K/dx (all lanes; per-lane row r=c21) =====
    float hph00=0.f, hph01=0.f, hph10=0.f, hph11=0.f;
#pragma unroll
    for(int k=0;k<12;++k){
      float2 hp = HPs2[cols[k]];
      hph00 += hp.x*H0[k]; hph01 += hp.x*H1[k];
      hph10 += hp.y*H0[k]; hph11 += hp.y*H1[k];
    }
    float s00 = hph00 + crm0, s01 = hph01, s10 = hph10, s11 = hph11 + crm1;
    float idet = 1.0f/(s00*s11 - s01*s10);
    float i00 =  s11*idet, i01 = -s01*idet, i10 = -s10*idet, i11 = s00*idet;
    float K0 = i00*hpr0 + i01*hpr1;
    float K1 = i10*hpr0 + i11*hpr1;
    // symmetrized S for the bitwise-symmetric quadratic term (uniform across lanes)
    float s01q = 0.5f*(s01 + s10);
    float dxval = K0*rr0 + K1*rr1;
    if (l<21){ Ks2[l] = make_float2(K0,K1); }
    // broadcast dx to all lanes
    float dxr[21];
    {
      int db = __float_as_int(dxval);
#pragma unroll
      for (int k=0;k<21;++k) dxr[k] = __int_as_float(__builtin_amdgcn_readlane(db, k));
    }
    __syncthreads();  // W2

    // ===== stage Pu: P = Pn_sym - [K[r].HP[:,c] + K[c].HP[:,r]] + K[r] Ssym K[c] =====
    // every term commutative-identical under r<->c => P exactly symmetric
    if (l<63){
      int r = c21;
#pragma unroll
      for (int s=0;s<7;++s){
        int j = (s<3)? (g21 + 3*s) : (cw + (s-3));
        float pnT = PnS[j*21 + r];      // Pn[j,r] (written by the (j,r)-lane)
        float2 hpj = HPs2[j];
        float2 kj  = Ks2[j];
        float base  = 0.5f*(pnv[s] + pnT);
        float cross = (K0*hpj.x + K1*hpj.y) + (kj.x*hpr0 + kj.y*hpr1);
        float quad  = (K0*kj.x)*s00 + (K0*kj.y + K1*kj.x)*s01q + (K1*kj.y)*s11;
        Pm[r*21+j] = base - cross + quad;
      }
    }

    // ===== state update (uniform; overlaps Pu LDS latency) =====
    float t2x = dxr[0]*dxr[0]+dxr[1]*dxr[1]+dxr[2]*dxr[2];
    float cX,k1X,k2X,j1X;
    if (t2x < 1e-4f){
      cX  = 1.f - t2x*(0.5f - t2x*((1.f/24.f) - t2x*(1.f/720.f)));
      k2X = 1.f - t2x*((1.f/6.f) - t2x*((1.f/120.f) - t2x*(1.f/5040.f)));
      k1X = 0.5f - t2x*((1.f/24.f) - t2x*(1.f/720.f));
      j1X = (1.f/6.f) - t2x*((1.f/120.f) - t2x*(1.f/5040.f));
    } else {
      float a = sqrtf(t2x);
      cX = __cosf(a);
      float s = __sinf(a);
      k2X = s/a; k1X = (1.f-cX)/t2x; j1X = (1.f-k2X)/t2x;
    }
    float dR[9];
    dR[0]=cX+k1X*dxr[0]*dxr[0];      dR[1]=k1X*dxr[0]*dxr[1]-k2X*dxr[2]; dR[2]=k1X*dxr[0]*dxr[2]+k2X*dxr[1];
    dR[3]=k1X*dxr[0]*dxr[1]+k2X*dxr[2]; dR[4]=cX+k1X*dxr[1]*dxr[1];      dR[5]=k1X*dxr[1]*dxr[2]-k2X*dxr[0];
    dR[6]=k1X*dxr[0]*dxr[2]-k2X*dxr[1]; dR[7]=k1X*dxr[1]*dxr[2]+k2X*dxr[0]; dR[8]=cX+k1X*dxr[2]*dxr[2];
    float Jm[9];
    Jm[0]=k2X+j1X*dxr[0]*dxr[0];      Jm[1]=j1X*dxr[0]*dxr[1]-k1X*dxr[2]; Jm[2]=j1X*dxr[0]*dxr[2]+k1X*dxr[1];
    Jm[3]=j1X*dxr[0]*dxr[1]+k1X*dxr[2]; Jm[4]=k2X+j1X*dxr[1]*dxr[1];      Jm[5]=j1X*dxr[1]*dxr[2]-k1X*dxr[0];
    Jm[6]=j1X*dxr[0]*dxr[2]-k1X*dxr[1]; Jm[7]=j1X*dxr[1]*dxr[2]+k1X*dxr[0]; Jm[8]=k2X+j1X*dxr[2]*dxr[2];

    float Ru[9]; mm33(Ru, dR, Rn);
    float vu0 = dR[0]*vn0+dR[1]*vn1+dR[2]*vn2 + Jm[0]*dxr[3]+Jm[1]*dxr[4]+Jm[2]*dxr[5];
    float vu1 = dR[3]*vn0+dR[4]*vn1+dR[5]*vn2 + Jm[3]*dxr[3]+Jm[4]*dxr[4]+Jm[5]*dxr[5];
    float vu2 = dR[6]*vn0+dR[7]*vn1+dR[8]*vn2 + Jm[6]*dxr[3]+Jm[7]*dxr[4]+Jm[8]*dxr[5];
    float pu0 = dR[0]*pn0+dR[1]*pn1+dR[2]*pn2 + Jm[0]*dxr[6]+Jm[1]*dxr[7]+Jm[2]*dxr[8];
    float pu1 = dR[3]*pn0+dR[4]*pn1+dR[5]*pn2 + Jm[3]*dxr[6]+Jm[4]*dxr[7]+Jm[5]*dxr[8];
    float pu2 = dR[6]*pn0+dR[7]*pn1+dR[8]*pn2 + Jm[6]*dxr[6]+Jm[7]*dxr[7]+Jm[8]*dxr[8];
    bw[0]+=dxr[9];  bw[1]+=dxr[10]; bw[2]+=dxr[11];
    ba[0]+=dxr[12]; ba[1]+=dxr[13]; ba[2]+=dxr[14];
    float Ec[9]; rot_from_t2(dxr[15]*dxr[15]+dxr[16]*dxr[16]+dxr[17]*dxr[17], dxr[15],dxr[16],dxr[17], Ec);
    float Rcu[9]; mm33(Rcu, Ec, Rc);
    tc[0]+=dxr[18]; tc[1]+=dxr[19]; tc[2]+=dxr[20];

    if (i==nx100){ normalize_rot9(Ru); nx100+=100; }
    if (i==nx1000){ normalize_rot9(Rcu); nx1000+=1000; }

#pragma unroll
    for(int k=0;k<9;++k){ Rt[k]=Ru[k]; Rc[k]=Rcu[k]; }
    vv[0]=vu0; vv[1]=vu1; vv[2]=vu2;
    pp[0]=pu0; pp[1]=pu1; pp[2]=pu2;

    __syncthreads();  // W3 (Pm writes visible before next-iter stage E reads)

    // ===== outputs =====
    float sv = pick_state(l, Rt, vv, pp, bw, ba, Rc, tc);
    if (l<33) op[i*ostr] = sv;
  }
}

extern "C" void kernel_launch(void* const* d_in, const int* in_sizes, int n_in,
                              void* d_out, int out_size, void* d_ws, size_t ws_size,
                              hipStream_t stream) {
  (void)n_in; (void)out_size; (void)d_ws; (void)ws_size;
  const float* t     = (const float*)d_in[0];
  const float* u     = (const float*)d_in[1];
  const float* mcov  = (const float*)d_in[2];
  const float* v_mes = (const float*)d_in[3];
  const float* ang0  = (const float*)d_in[5];
  int N = in_sizes[0];
  iekf_scan_kernel<<<dim3(1), dim3(64), 0, stream>>>(t, u, mcov, v_mes, ang0, (float*)d_out, N);
}

// Round 5
// 45596.231 us; speedup vs baseline: 1.1824x; 1.0100x over previous
//
#include <hip/hip_runtime.h>

#define GRAV 9.80665f
// Single-wave block: all LDS ops drain with lgkmcnt; no s_barrier, no vmcnt
// drain (prefetch loads / output stores stay in flight). "memory" clobber
// keeps the compiler from moving LDS ops across; sched_barrier pins order.
#define WAVE_SYNC() do { \
    asm volatile("s_waitcnt lgkmcnt(0)" ::: "memory"); \
    __builtin_amdgcn_sched_barrier(0); \
  } while(0)

__device__ __forceinline__ float sel3(int r, float a0, float a1, float a2){
  float x = (r==1)? a1 : a0;
  return (r>=2)? a2 : x;
}

__device__ __forceinline__ void mm33(float* __restrict__ O, const float* A, const float* B){
#pragma unroll
  for(int r=0;r<3;++r){
#pragma unroll
    for(int c=0;c<3;++c){
      O[r*3+c] = A[r*3+0]*B[0*3+c] + A[r*3+1]*B[1*3+c] + A[r*3+2]*B[2*3+c];
    }
  }
}

// R = c*I + k1*phi phi^T + k2*skew(phi); Taylor for small t=|phi|^2, exact otherwise.
__device__ __forceinline__ void rot_from_t2(float t_, float p0, float p1, float p2, float* R){
  float c_, k1_, k2_;
  if (t_ < 1e-4f){
    c_  = 1.f - t_*(0.5f - t_*((1.f/24.f) - t_*(1.f/720.f)));
    k2_ = 1.f - t_*((1.f/6.f) - t_*((1.f/120.f) - t_*(1.f/5040.f)));
    k1_ = 0.5f - t_*((1.f/24.f) - t_*(1.f/720.f));
  } else {
    float a = sqrtf(t_);
    c_ = __cosf(a);
    float s = __sinf(a);
    k2_ = s/a;
    k1_ = (1.f - c_)/t_;
  }
  R[0]=c_+k1_*p0*p0;      R[1]=k1_*p0*p1-k2_*p2;  R[2]=k1_*p0*p2+k2_*p1;
  R[3]=k1_*p0*p1+k2_*p2;  R[4]=c_+k1_*p1*p1;      R[5]=k1_*p1*p2-k2_*p0;
  R[6]=k1_*p0*p2-k2_*p1;  R[7]=k1_*p1*p2+k2_*p0;  R[8]=c_+k1_*p2*p2;
}

__device__ __forceinline__ void normalize_rot9(float* X){
#pragma unroll 1
  for(int it=0; it<8; ++it){
    float Y[9], Z[9];
#pragma unroll
    for(int r=0;r<3;++r)
#pragma unroll
      for(int c=0;c<3;++c)
        Y[r*3+c] = X[r*3+0]*X[c*3+0] + X[r*3+1]*X[c*3+1] + X[r*3+2]*X[c*3+2];
#pragma unroll
    for(int r=0;r<3;++r)
#pragma unroll
      for(int c=0;c<3;++c)
        Z[r*3+c] = Y[r*3+0]*X[0*3+c] + Y[r*3+1]*X[1*3+c] + Y[r*3+2]*X[2*3+c];
#pragma unroll
    for(int e=0;e<9;++e) X[e] = 1.5f*X[e] - 0.5f*Z[e];
  }
}

__device__ __forceinline__ float pick_state(int l,
    const float* Rt, const float* vv, const float* pp,
    const float* bw, const float* ba, const float* Rc, const float* tc){
  float s = Rt[0];
  s=(l==1)?Rt[1]:s;  s=(l==2)?Rt[2]:s;  s=(l==3)?Rt[3]:s;  s=(l==4)?Rt[4]:s;
  s=(l==5)?Rt[5]:s;  s=(l==6)?Rt[6]:s;  s=(l==7)?Rt[7]:s;  s=(l==8)?Rt[8]:s;
  s=(l==9)?vv[0]:s;  s=(l==10)?vv[1]:s; s=(l==11)?vv[2]:s;
  s=(l==12)?pp[0]:s; s=(l==13)?pp[1]:s; s=(l==14)?pp[2]:s;
  s=(l==15)?bw[0]:s; s=(l==16)?bw[1]:s; s=(l==17)?bw[2]:s;
  s=(l==18)?ba[0]:s; s=(l==19)?ba[1]:s; s=(l==20)?ba[2]:s;
  s=(l==21)?Rc[0]:s; s=(l==22)?Rc[1]:s; s=(l==23)?Rc[2]:s;
  s=(l==24)?Rc[3]:s; s=(l==25)?Rc[4]:s; s=(l==26)?Rc[5]:s;
  s=(l==27)?Rc[6]:s; s=(l==28)?Rc[7]:s; s=(l==29)?Rc[8]:s;
  s=(l==30)?tc[0]:s; s=(l==31)?tc[1]:s; s=(l==32)?tc[2]:s;
  return s;
}

__global__ __launch_bounds__(64,1)
void iekf_scan_kernel(const float* __restrict__ t,
                      const float* __restrict__ u,
                      const float* __restrict__ mcov,
                      const float* __restrict__ v_mes,
                      const float* __restrict__ ang0,
                      float* __restrict__ out, int N)
{
  const int l = threadIdx.x;
  __shared__ float  Pm[441];    // canonical symmetric P
  __shared__ float  Eb[441];    // E = Phi @ M
  __shared__ float  PnS[441];   // P_n (raw, for transpose reads)
  __shared__ float2 HPs2[21];   // HP[:,c] pairs

  // ---- initial state (uniform across lanes) ----
  float Rt[9], vv[3], pp[3], bw[3], ba[3], Rc[9], tc[3];
  {
    float rl = ang0[0], pt = ang0[1], yw = ang0[2];
    float cr=cosf(rl), sr=sinf(rl), cp=cosf(pt), sp=sinf(pt), cy=cosf(yw), sy=sinf(yw);
    Rt[0]=cy*cp; Rt[1]=cy*sp*sr - sy*cr; Rt[2]=cy*sp*cr + sy*sr;
    Rt[3]=sy*cp; Rt[4]=sy*sp*sr + cy*cr; Rt[5]=sy*sp*cr - cy*sr;
    Rt[6]=-sp;   Rt[7]=cp*sr;            Rt[8]=cp*cr;
  }
  vv[0]=v_mes[0]; vv[1]=v_mes[1]; vv[2]=v_mes[2];
#pragma unroll
  for(int k=0;k<3;++k){ pp[k]=0.f; bw[k]=0.f; ba[k]=0.f; tc[k]=0.f; }
  Rc[0]=1.f;Rc[1]=0.f;Rc[2]=0.f;Rc[3]=0.f;Rc[4]=1.f;Rc[5]=0.f;Rc[6]=0.f;Rc[7]=0.f;Rc[8]=1.f;

  // ---- init covariance ----
  for (int e=l; e<441; e+=64){
    int r=e/21, c=e-(e/21)*21;
    float vI=0.f;
    if (r==c){
      if (r<2) vI=0.001f;
      else if (r==3||r==4) vI=0.1f;
      else if (r>=9&&r<12) vI=0.006f;
      else if (r>=12&&r<15) vI=0.004f;
      else if (r>=15&&r<18) vI=1e-6f;
      else if (r>=18) vI=0.005f;
    }
    Pm[e]=vI;
  }

  // ---- per-lane output mapping ----
  int ostr=0; float* op = out;
  {
    int obase=0, ooff=0;
    if (l<9)       {obase=0;    ostr=9; ooff=l;}
    else if (l<12) {obase=9*N;  ostr=3; ooff=l-9;}
    else if (l<15) {obase=12*N; ostr=3; ooff=l-12;}
    else if (l<18) {obase=15*N; ostr=3; ooff=l-15;}
    else if (l<21) {obase=18*N; ostr=3; ooff=l-18;}
    else if (l<30) {obase=21*N; ostr=9; ooff=l-21;}
    else           {obase=30*N; ostr=3; ooff=l-30;}
    op = out + obase + ooff;
  }

  const int g21 = l/21;        // group 0..2 (3 for lane 63, masked out)
  const int c21 = l - g21*21;  // 0..20 : column (stage E) / row (Pn,Pu)
  const int cw  = 9 + 4*g21;   // copy-block base row/col
  int l1 = l+21; if (l1>=63) l1-=63;
  int l2 = l+42; if (l2>=63) l2-=63;

  static const int cols[12] = {3,4,5, 9,10,11, 15,16,17, 18,19,20};

  // ---- row 0 outputs ----
  {
    float sv = pick_state(l, Rt, vv, pp, bw, ba, Rc, tc);
    if (l<33) op[0] = sv;
  }
  __syncthreads();

  // ---- prefetch for i=1 ----
  float tA = t[0], tB = t[1];
  float cu[6];
#pragma unroll
  for(int k=0;k<6;++k) cu[k]=u[6+k];
  float cm0=mcov[2], cm1=mcov[3];

  int nx100=100, nx1000=1000;

#pragma unroll 1
  for (int i=1; i<N; ++i){
    float dt = tB - tA;
    float u0=cu[0], u1=cu[1], u2=cu[2], u3=cu[3], u4=cu[4], u5=cu[5];
    float crm0=cm0, crm1=cm1;
    if (i+1 < N){
      tA = tB; tB = t[i+1];
#pragma unroll
      for(int k=0;k<6;++k) cu[k]=u[(i+1)*6+k];
      cm0 = mcov[(i+1)*2]; cm1 = mcov[(i+1)*2+1];
    }
    float dt2=dt*dt, gdt=GRAV*dt, hdt=0.5f*dt, g6=gdt*dt*(1.0f/6.0f), hdt2=0.5f*dt*dt;

    // ===== uniform small math (all lanes redundant) =====
    float w0=u0-bw[0], w1=u1-bw[1], w2=u2-bw[2];
    float aa0=u3-ba[0], aa1=u4-ba[1], aa2=u5-ba[2];
    float acc0 = Rt[0]*aa0+Rt[1]*aa1+Rt[2]*aa2;
    float acc1 = Rt[3]*aa0+Rt[4]*aa1+Rt[5]*aa2;
    float acc2 = Rt[6]*aa0+Rt[7]*aa1+Rt[8]*aa2 - GRAV;
    float vn0=vv[0]+acc0*dt, vn1=vv[1]+acc1*dt, vn2=vv[2]+acc2*dt;
    float pn0=pp[0]+vv[0]*dt+acc0*hdt2;
    float pn1=pp[1]+vv[1]*dt+acc1*hdt2;
    float pn2=pp[2]+vv[2]*dt+acc2*hdt2;
    float ph0=w0*dt, ph1=w1*dt, ph2=w2*dt;
    float dRs[9]; rot_from_t2(ph0*ph0+ph1*ph1+ph2*ph2, ph0,ph1,ph2, dRs);
    float Rn[9]; mm33(Rn, Rt, dRs);          // Rot_n
    float Rb[9]; mm33(Rb, Rn, Rc);           // Rot_body
    float vi0 = Rn[0]*vn0+Rn[3]*vn1+Rn[6]*vn2;  // v_imu = Rot_n^T v_n
    float vi1 = Rn[1]*vn0+Rn[4]*vn1+Rn[7]*vn2;
    float vi2 = Rn[2]*vn0+Rn[5]*vn1+Rn[8]*vn2;
    float vb1 = Rc[1]*vi0+Rc[4]*vi1+Rc[7]*vi2 + (tc[2]*w0 - tc[0]*w2);
    float vb2 = Rc[2]*vi0+Rc[5]*vi1+Rc[8]*vi2 + (tc[0]*w1 - tc[1]*w0);
    float rr0 = -vb1, rr1 = -vb2;

    float H0[12], H1[12];
    H0[0]=Rb[1]; H0[1]=Rb[4]; H0[2]=Rb[7];
    H1[0]=Rb[2]; H1[1]=Rb[5]; H1[2]=Rb[8];
    H0[3]=tc[2];  H0[4]=0.f;   H0[5]=-tc[0];
    H1[3]=-tc[1]; H1[4]=tc[0]; H1[5]=0.f;
    H0[6]=Rc[4]*vi2 - Rc[7]*vi1;  H0[7]=Rc[7]*vi0 - Rc[1]*vi2;  H0[8]=Rc[1]*vi1 - Rc[4]*vi0;
    H1[6]=Rc[5]*vi2 - Rc[8]*vi1;  H1[7]=Rc[8]*vi0 - Rc[2]*vi2;  H1[8]=Rc[2]*vi1 - Rc[5]*vi0;
    H0[9]=-w2; H0[10]=0.f; H0[11]=w0;
    H1[9]=w1;  H1[10]=-w0; H1[11]=0.f;

    // Phi off-diag blocks (uniform): B=-Rot*dt, Cab=C+AB/2, D2=D+dtC/2+dtAB/6
    float Bm[9], Cab[9], D2a[9];
#pragma unroll
    for(int k=0;k<3;++k){
      float b0=-dt*Rt[k], b1=-dt*Rt[3+k], b2=-dt*Rt[6+k];
      float c0=dt*(vv[2]*Rt[3+k]-vv[1]*Rt[6+k]);
      float c1=dt*(vv[0]*Rt[6+k]-vv[2]*Rt[k]);
      float c2=dt*(vv[1]*Rt[k]-vv[0]*Rt[3+k]);
      float d0=dt*(pp[2]*Rt[3+k]-pp[1]*Rt[6+k]);
      float d1=dt*(pp[0]*Rt[6+k]-pp[2]*Rt[k]);
      float d2=dt*(pp[1]*Rt[k]-pp[0]*Rt[3+k]);
      Bm[k]=b0; Bm[3+k]=b1; Bm[6+k]=b2;
      Cab[k]=c0+0.5f*gdt*b1; Cab[3+k]=c1-0.5f*gdt*b0; Cab[6+k]=c2;
      D2a[k]=d0+hdt*c0+g6*b1; D2a[3+k]=d1+hdt*c1-g6*b0; D2a[6+k]=d2+hdt*c2;
    }
    float Bs0=sel3(g21,Bm[0],Bm[3],Bm[6]),  Bs1=sel3(g21,Bm[1],Bm[4],Bm[7]),  Bs2=sel3(g21,Bm[2],Bm[5],Bm[8]);
    float Cs0=sel3(g21,Cab[0],Cab[3],Cab[6]),Cs1=sel3(g21,Cab[1],Cab[4],Cab[7]),Cs2=sel3(g21,Cab[2],Cab[5],Cab[8]);
    float Ds0=sel3(g21,D2a[0],D2a[3],D2a[6]),Ds1=sel3(g21,D2a[1],D2a[4],D2a[7]),Ds2=sel3(g21,D2a[2],D2a[5],D2a[8]);

    // GQG^T delta constants (uniform): RR^T and scaled q's
    float RRT00=Rt[0]*Rt[0]+Rt[1]*Rt[1]+Rt[2]*Rt[2];
    float RRT01=Rt[0]*Rt[3]+Rt[1]*Rt[4]+Rt[2]*Rt[5];
    float RRT02=Rt[0]*Rt[6]+Rt[1]*Rt[7]+Rt[2]*Rt[8];
    float RRT11=Rt[3]*Rt[3]+Rt[4]*Rt[4]+Rt[5]*Rt[5];
    float RRT12=Rt[3]*Rt[6]+Rt[4]*Rt[7]+Rt[5]*Rt[8];
    float RRT22=Rt[6]*Rt[6]+Rt[7]*Rt[7]+Rt[8]*Rt[8];
    float q0d=0.001f*dt2, q1d=0.01f*dt2;
    float q69=6e-9f*dt2, q24=2e-4f*dt2, q19=1e-9f*dt2;

    // ===== stage E: E = Phi @ (P + GQG^T), GQG^T folded into reads =====
    if (l<63){
      int c = c21;
      bool cl3 = (c<3);
      bool c36 = (c>=3 && c<6);
      float R0c  = sel3(c,   RRT00, RRT01, RRT02);
      float R1c  = sel3(c,   RRT01, RRT11, RRT12);
      float R2c  = sel3(c,   RRT02, RRT12, RRT22);
      float R0c3 = sel3(c-3, RRT00, RRT01, RRT02);
      float R1c3 = sel3(c-3, RRT01, RRT11, RRT12);
      float R2c3 = sel3(c-3, RRT02, RRT12, RRT22);
      float d0  = cl3 ? q0d*R0c : 0.f;
      float d1  = cl3 ? q0d*R1c : 0.f;
      float dg  = cl3 ? q0d*sel3(g21,R0c,R1c,R2c) : 0.f;
      float dg3 = c36 ? q1d*sel3(g21,R0c3,R1c3,R2c3) : 0.f;

      float m0  = Pm[c]            + d0;
      float m1  = Pm[21+c]         + d1;
      float mr  = Pm[g21*21+c]     + dg;
      float m3r = Pm[(3+g21)*21+c] + dg3;
      float m6r = Pm[(6+g21)*21+c];
      float m9  = Pm[9*21+c]  + ((c==9) ? q69 : 0.f);
      float m10 = Pm[10*21+c] + ((c==10)? q69 : 0.f);
      float m11 = Pm[11*21+c] + ((c==11)? q69 : 0.f);
      float m12 = Pm[12*21+c] + ((c==12)? q24 : 0.f);
      float m13 = Pm[13*21+c] + ((c==13)? q24 : 0.f);
      float m14 = Pm[14*21+c] + ((c==14)? q24 : 0.f);

      float Ar = (g21==0)? gdt*m1 : (g21==1)? -gdt*m0 : 0.f;
      float bterm = Bs0*m12+Bs1*m13+Bs2*m14;
      float e0 = mr + Bs0*m9+Bs1*m10+Bs2*m11;
      float e1 = m3r + Ar + Cs0*m9+Cs1*m10+Cs2*m11 + bterm;
      float e2 = m6r + hdt*Ar + dt*m3r + Ds0*m9+Ds1*m10+Ds2*m11 + hdt*bterm;
      Eb[g21*21+c]=e0; Eb[(3+g21)*21+c]=e1; Eb[(6+g21)*21+c]=e2;
#pragma unroll
      for (int jj=0;jj<4;++jj){
        int row = cw+jj;
        float qd = (row<12)? q69 : (row<15)? q24 : q19;
        Eb[row*21+c] = Pm[row*21+c] + ((row==c)? qd : 0.f);
      }
    }
    WAVE_SYNC();  // W0

    // ===== stage Pn: row r of P_n in registers (+LDS for transpose) + HP partials =====
    float pnv[7];
#pragma unroll
    for(int k=0;k<7;++k) pnv[k]=0.f;
    float p0=0.f, p1=0.f;
    if (l<63){
      int r = c21;
      const float* Er = Eb + r*21;
      float e0a=Er[0], e1a=Er[1];
      float eg=Er[g21], e3g=Er[3+g21], e6g=Er[6+g21];
      float e9=Er[9],e10=Er[10],e11=Er[11],e12=Er[12],e13=Er[13],e14=Er[14];
      float Ag = (g21==0)? gdt*e1a : (g21==1)? -gdt*e0a : 0.f;
      float bterm = Bs0*e12+Bs1*e13+Bs2*e14;
      pnv[0] = eg + Bs0*e9+Bs1*e10+Bs2*e11;                             // col g
      pnv[1] = e3g + Ag + Cs0*e9+Cs1*e10+Cs2*e11 + bterm;               // col 3+g
      pnv[2] = e6g + hdt*Ag + dt*e3g + Ds0*e9+Ds1*e10+Ds2*e11 + hdt*bterm; // col 6+g
      pnv[3] = Er[cw]; pnv[4] = Er[cw+1]; pnv[5] = Er[cw+2]; pnv[6] = Er[cw+3];

      // store Pn row to LDS for bitwise-symmetric transpose reads in stage Pu
      PnS[r*21 + g21]     = pnv[0];
      PnS[r*21 + 3+g21]   = pnv[1];
      PnS[r*21 + 6+g21]   = pnv[2];
      PnS[r*21 + cw]      = pnv[3];
      PnS[r*21 + cw+1]    = pnv[4];
      PnS[r*21 + cw+2]    = pnv[5];
      PnS[r*21 + cw+3]    = pnv[6];

      // HP partial: this group's share of sum_k H[a,k]*Pn[r, cols[k]]
      float c1a = sel3(g21, H0[0], H0[1], H0[2]);
      float c3a = sel3(g21, H0[3], 0.f,   H0[8]);
      float c4a = sel3(g21, H0[4], 0.f,   H0[9]);
      float c5a = sel3(g21, H0[5], H0[6], H0[10]);
      float c6a = sel3(g21, 0.f,   H0[7], H0[11]);
      float c1b = sel3(g21, H1[0], H1[1], H1[2]);
      float c3b = sel3(g21, H1[3], 0.f,   H1[8]);
      float c4b = sel3(g21, H1[4], 0.f,   H1[9]);
      float c5b = sel3(g21, H1[5], H1[6], H1[10]);
      float c6b = sel3(g21, 0.f,   H1[7], H1[11]);
      p0 = c1a*pnv[1] + c3a*pnv[3] + c4a*pnv[4] + c5a*pnv[5] + c6a*pnv[6];
      p1 = c1b*pnv[1] + c3b*pnv[3] + c4b*pnv[4] + c5b*pnv[5] + c6b*pnv[6];
    }
    // combine partials across the 3 groups; every lane ends with HP[:,r], r=c21
    float hpr0 = p0 + __shfl(p0, l1) + __shfl(p0, l2);
    float hpr1 = p1 + __shfl(p1, l1) + __shfl(p1, l2);
    if (l<21) HPs2[c21] = make_float2(hpr0, hpr1);
    WAVE_SYNC();  // W1

    // ===== stage S/K/dx + Pu, fused (no barrier needed between) =====
    float hph00=0.f, hph01=0.f, hph10=0.f, hph11=0.f;
#pragma unroll
    for(int k=0;k<12;++k){
      float2 hp = HPs2[cols[k]];
      hph00 += hp.x*H0[k]; hph01 += hp.x*H1[k];
      hph10 += hp.y*H0[k]; hph11 += hp.y*H1[k];
    }
    float s00 = hph00 + crm0, s01 = hph01, s10 = hph10, s11 = hph11 + crm1;
    float idet = 1.0f/(s00*s11 - s01*s10);
    float i00 =  s11*idet, i01 = -s01*idet, i10 = -s10*idet, i11 = s00*idet;
    float K0 = i00*hpr0 + i01*hpr1;
    float K1 = i10*hpr0 + i11*hpr1;
    // symmetrized S for the bitwise-symmetric quadratic term (uniform across lanes)
    float s01q = 0.5f*(s01 + s10);
    float dxval = K0*rr0 + K1*rr1;
    // broadcast dx to all lanes
    float dxr[21];
    {
      int db = __float_as_int(dxval);
#pragma unroll
      for (int k=0;k<21;++k) dxr[k] = __int_as_float(__builtin_amdgcn_readlane(db, k));
    }

    // ===== stage Pu: P = Pn_sym - [K[r].HP[:,c] + K[c].HP[:,r]] + K[r] Ssym K[c] =====
    // K[j] reconstructed in-lane from HPs2[j] (i00..i11 lane-uniform => bit-identical
    // to lane j's own K). Every term commutative-identical under r<->c =>
    // P exactly symmetric.
    if (l<63){
      int r = c21;
#pragma unroll
      for (int s=0;s<7;++s){
        int j = (s<3)? (g21 + 3*s) : (cw + (s-3));
        float pnT = PnS[j*21 + r];      // Pn[j,r] (written by the (j,r)-lane)
        float2 hpj = HPs2[j];
        float kjx = i00*hpj.x + i01*hpj.y;
        float kjy = i10*hpj.x + i11*hpj.y;
        float base  = 0.5f*(pnv[s] + pnT);
        float cross = (K0*hpj.x + K1*hpj.y) + (kjx*hpr0 + kjy*hpr1);
        float quad  = (K0*kjx)*s00 + (K0*kjy + K1*kjx)*s01q + (K1*kjy)*s11;
        Pm[r*21+j] = base - cross + quad;
      }
    }

    // ===== state update (uniform; overlaps Pu LDS latency) =====
    float t2x = dxr[0]*dxr[0]+dxr[1]*dxr[1]+dxr[2]*dxr[2];
    float cX,k1X,k2X,j1X;
    if (t2x < 1e-4f){
      cX  = 1.f - t2x*(0.5f - t2x*((1.f/24.f) - t2x*(1.f/720.f)));
      k2X = 1.f - t2x*((1.f/6.f) - t2x*((1.f/120.f) - t2x*(1.f/5040.f)));
      k1X = 0.5f - t2x*((1.f/24.f) - t2x*(1.f/720.f));
      j1X = (1.f/6.f) - t2x*((1.f/120.f) - t2x*(1.f/5040.f));
    } else {
      float a = sqrtf(t2x);
      cX = __cosf(a);
      float s = __sinf(a);
      k2X = s/a; k1X = (1.f-cX)/t2x; j1X = (1.f-k2X)/t2x;
    }
    float dR[9];
    dR[0]=cX+k1X*dxr[0]*dxr[0];      dR[1]=k1X*dxr[0]*dxr[1]-k2X*dxr[2]; dR[2]=k1X*dxr[0]*dxr[2]+k2X*dxr[1];
    dR[3]=k1X*dxr[0]*dxr[1]+k2X*dxr[2]; dR[4]=cX+k1X*dxr[1]*dxr[1];      dR[5]=k1X*dxr[1]*dxr[2]-k2X*dxr[0];
    dR[6]=k1X*dxr[0]*dxr[2]-k2X*dxr[1]; dR[7]=k1X*dxr[1]*dxr[2]+k2X*dxr[0]; dR[8]=cX+k1X*dxr[2]*dxr[2];
    float Jm[9];
    Jm[0]=k2X+j1X*dxr[0]*dxr[0];      Jm[1]=j1X*dxr[0]*dxr[1]-k1X*dxr[2]; Jm[2]=j1X*dxr[0]*dxr[2]+k1X*dxr[1];
    Jm[3]=j1X*dxr[0]*dxr[1]+k1X*dxr[2]; Jm[4]=k2X+j1X*dxr[1]*dxr[1];      Jm[5]=j1X*dxr[1]*dxr[2]-k1X*dxr[0];
    Jm[6]=j1X*dxr[0]*dxr[2]-k1X*dxr[1]; Jm[7]=j1X*dxr[1]*dxr[2]+k1X*dxr[0]; Jm[8]=k2X+j1X*dxr[2]*dxr[2];

    float Ru[9]; mm33(Ru, dR, Rn);
    float vu0 = dR[0]*vn0+dR[1]*vn1+dR[2]*vn2 + Jm[0]*dxr[3]+Jm[1]*dxr[4]+Jm[2]*dxr[5];
    float vu1 = dR[3]*vn0+dR[4]*vn1+dR[5]*vn2 + Jm[3]*dxr[3]+Jm[4]*dxr[4]+Jm[5]*dxr[5];
    float vu2 = dR[6]*vn0+dR[7]*vn1+dR[8]*vn2 + Jm[6]*dxr[3]+Jm[7]*dxr[4]+Jm[8]*dxr[5];
    float pu0 = dR[0]*pn0+dR[1]*pn1+dR[2]*pn2 + Jm[0]*dxr[6]+Jm[1]*dxr[7]+Jm[2]*dxr[8];
    float pu1 = dR[3]*pn0+dR[4]*pn1+dR[5]*pn2 + Jm[3]*dxr[6]+Jm[4]*dxr[7]+Jm[5]*dxr[8];
    float pu2 = dR[6]*pn0+dR[7]*pn1+dR[8]*pn2 + Jm[6]*dxr[6]+Jm[7]*dxr[7]+Jm[8]*dxr[8];
    bw[0]+=dxr[9];  bw[1]+=dxr[10]; bw[2]+=dxr[11];
    ba[0]+=dxr[12]; ba[1]+=dxr[13]; ba[2]+=dxr[14];
    float Ec[9]; rot_from_t2(dxr[15]*dxr[15]+dxr[16]*dxr[16]+dxr[17]*dxr[17], dxr[15],dxr[16],dxr[17], Ec);
    float Rcu[9]; mm33(Rcu, Ec, Rc);
    tc[0]+=dxr[18]; tc[1]+=dxr[19]; tc[2]+=dxr[20];

    if (i==nx100){ normalize_rot9(Ru); nx100+=100; }
    if (i==nx1000){ normalize_rot9(Rcu); nx1000+=1000; }

#pragma unroll
    for(int k=0;k<9;++k){ Rt[k]=Ru[k]; Rc[k]=Rcu[k]; }
    vv[0]=vu0; vv[1]=vu1; vv[2]=vu2;
    pp[0]=pu0; pp[1]=pu1; pp[2]=pu2;

    WAVE_SYNC();  // W3 (Pm writes visible before next-iter stage E reads)

    // ===== outputs =====
    float sv = pick_state(l, Rt, vv, pp, bw, ba, Rc, tc);
    if (l<33) op[i*ostr] = sv;
  }
}

extern "C" void kernel_launch(void* const* d_in, const int* in_sizes, int n_in,
                              void* d_out, int out_size, void* d_ws, size_t ws_size,
                              hipStream_t stream) {
  (void)n_in; (void)out_size; (void)d_ws; (void)ws_size;
  const float* t     = (const float*)d_in[0];
  const float* u     = (const float*)d_in[1];
  const float* mcov  = (const float*)d_in[2];
  const float* v_mes = (const float*)d_in[3];
  const float* ang0  = (const float*)d_in[5];
  int N = in_sizes[0];
  iekf_scan_kernel<<<dim3(1), dim3(64), 0, stream>>>(t, u, mcov, v_mes, ang0, (float*)d_out, N);
}